// Round 5
// baseline (1186.292 us; speedup 1.0000x reference)
//
#include <hip/hip_runtime.h>
#include <stdint.h>

#define N_NODES 200000
#define NPL     12500
#define NLVL    16
#define DEG     8
#define EPL     (NPL*DEG)     // 100000
#define HD      128
#define KTOT    256           // concat K: [x | m]
#define MT      64            // rows per block (verified best)
#define NBLK    196           // ceil(12500/64)
#define GRID    (2*NBLK)      // 392 blocks: <= 2/CU * 256 CU -> all resident
#define ASTR    264           // A-tile row stride (bf16), +8 pad
#define WTL     98304         // Wt elems per layer: 192 tiles x 64 lanes x 8

typedef unsigned short u16;
typedef unsigned int   u32;

typedef __attribute__((ext_vector_type(8)))  short  short8;   // 8 bf16 = 4 VGPR (MFMA A/B frag)
typedef __attribute__((ext_vector_type(16))) float  f32x16;   // 32x32 MFMA C/D frag

__device__ __forceinline__ float bf2f(u32 u) { return __uint_as_float(u << 16); }
__device__ __forceinline__ float bflo(u32 u) { return __uint_as_float(u << 16); }
__device__ __forceinline__ float bfhi(u32 u) { return __uint_as_float(u & 0xFFFF0000u); }
__device__ __forceinline__ u16 f2bf(float f) {
  u32 u = __float_as_uint(f);
  return (u16)((u + 0x7FFFu + ((u >> 16) & 1u)) >> 16);   // RNE
}
__device__ __forceinline__ u32 pack2(float a, float b) {
  u32 ua = __float_as_uint(a), ub = __float_as_uint(b);
  ua = (ua + 0x7FFFu + ((ua >> 16) & 1u)) >> 16;
  ub = ((ub + 0x7FFFu + ((ub >> 16) & 1u)) >> 16) << 16;
  return ua | ub;
}
__device__ __forceinline__ float fsig(float x) {
  return __builtin_amdgcn_rcpf(1.f + __builtin_amdgcn_exp2f(-1.4426950408889634f * x));
}
__device__ __forceinline__ float ftanh(float x) {
  float t = __builtin_amdgcn_exp2f(2.8853900817779268f * x);   // e^(2x)
  return 1.f - 2.f * __builtin_amdgcn_rcpf(t + 1.f);           // inf-safe at both ends
}

// x init: x[index_map[i]] = bf16(features[i])
__global__ __launch_bounds__(256) void scatter_x(const float* __restrict__ f,
    const int* __restrict__ idx, u16* __restrict__ xb)
{
  const int t = blockIdx.x * 256 + threadIdx.x;   // 3.2M threads, 16 per row
  const int i = t >> 4, sg = (t & 15) * 8;
  const int d = idx[i];
  const float4 a = *(const float4*)(f + (size_t)i * HD + sg);
  const float4 b = *(const float4*)(f + (size_t)i * HD + sg + 4);
  uint4 o;
  o.x = pack2(a.x, a.y); o.y = pack2(a.z, a.w);
  o.z = pack2(b.x, b.y); o.w = pack2(b.z, b.w);
  *(uint4*)(xb + (size_t)d * HD + sg) = o;
}

// out[i] = fp32(h_final[index_map[i]])
__global__ __launch_bounds__(256) void gather_out(const u16* __restrict__ hb,
    const int* __restrict__ idx, float* __restrict__ o)
{
  const int t = blockIdx.x * 256 + threadIdx.x;
  const int i = t >> 4, sg = (t & 15) * 8;
  const int s = idx[i];
  const uint4 v = *(const uint4*)(hb + (size_t)s * HD + sg);
  float4 lo, hi;
  lo.x = bflo(v.x); lo.y = bfhi(v.x); lo.z = bflo(v.y); lo.w = bfhi(v.y);
  hi.x = bflo(v.z); hi.y = bfhi(v.z); hi.z = bflo(v.w); hi.w = bfhi(v.w);
  *(float4*)(o + (size_t)i * HD + sg)     = lo;
  *(float4*)(o + (size_t)i * HD + sg + 4) = hi;
}

// Fragment-major Wt (see Round-4 comment) + zero the barrier counter each
// graph replay (stream-ordered before level_all).
__global__ __launch_bounds__(256) void build_wt(const float* __restrict__ wx,
    const float* __restrict__ wh, u16* __restrict__ wt, int* __restrict__ done)
{
  const int t = blockIdx.x * 256 + threadIdx.x;   // < 196608
  if (t < 4) done[t] = 0;
  const int l = t / WTL;
  const int r = t - l * WTL;
  const int e = r & 7;
  const int chunk = r >> 3;
  const int lane = chunk & 63;
  const int tile = chunk >> 6;          // 0..191
  const int l31 = lane & 31, lq = lane >> 5;
  int col, k;
  if (tile < 128)      { col =       (tile >> 4) * 32 + l31; k =       (tile & 15) * 16 + lq * 8 + e; }
  else if (tile < 160) { col = 256 + ((tile - 128) >> 3) * 32 + l31; k = ((tile - 128) & 7) * 16 + lq * 8 + e; }
  else                 { col = 384 + ((tile - 160) >> 3) * 32 + l31; k = 128 + ((tile - 160) & 7) * 16 + lq * 8 + e; }
  float v;
  if (col < 384) {   // RZ full-K, GXN (k<128 by construction)
    v = (k < 128) ? wx[(size_t)(l * 128 + k) * 384 + col]
                  : wh[(size_t)l * 49152 + (size_t)(k - 128) * 384 + col];
  } else {           // GHN (k>=128 by construction)
    v = wh[(size_t)l * 49152 + (size_t)(k - 128) * 384 + (col - 128)];
  }
  wt[(size_t)l * WTL + r] = f2bf(v);
}

// Persistent kernel, plain launch (graph-capture safe): all 17 stages in
// one dispatch, separated by a software global barrier.
//   - GRID=392 blocks, launch_bounds(256,2), LDS 33.8KB -> >=2 blocks/CU by
//     resource math -> all blocks resident whatever the dispatch order ->
//     spin barrier cannot deadlock.
//   - Barrier: monotonic counter. Writer: stores drained by __syncthreads()
//     (compiler emits vmcnt(0) before s_barrier), then thread0 does a
//     RELEASE fetch_add at agent scope (XCD-L2 writeback). Waiter: thread0
//     RELAXED-spins (no L2-inv thrash while stragglers run), then one
//     agent ACQUIRE fence (L1+L2 invalidate) + __syncthreads().
// Stage body is byte-identical to the verified 644.7us level_step.
__global__ __launch_bounds__(256, 2) void level_all(
    u16* __restrict__ bufA, u16* __restrict__ bufB,
    const u16* __restrict__ wt, const float* __restrict__ bias,
    const int* __restrict__ esrc, int* done)
{
  __shared__ __align__(16) u16 sA[MT * ASTR];     // 33,792 B

  const int blk0 = blockIdx.x;
  const int layer = (blk0 < NBLK) ? 0 : 1;
  const int blk   = (blk0 < NBLK) ? blk0 : blk0 - NBLK;

  const u16*   x  = layer ? bufB : bufA;          // L0: scattered x; L1: h0
  u16*         h  = layer ? bufA : bufB;          // L0: h0; L1: h1 (final)
  const u16*   Wt = wt  + (size_t)layer * WTL;
  const float* bs = bias + (size_t)layer * 384;

  const int tid = threadIdx.x;
  const int wv = tid >> 6, lane = tid & 63;
  const int l31 = lane & 31, lq = lane >> 5;

  // stage-invariant hoists
  const float b0 = bs[      32 * wv + l31];
  const float b1 = bs[128 + 32 * wv + l31];
  const float b2 = bs[256 + 32 * wv + l31];
  const u16* wlane = Wt + (size_t)lane * 8;
  const int jcol = 32 * wv + l31;

  for (int stage = 0; stage <= NLVL; ++stage) {
    // ---- global barrier: wait for all GRID blocks of stage-1 ----
    if (stage > 0) {
      if (tid == 0) {
        const int target = GRID * stage;
        while (__hip_atomic_load(done, __ATOMIC_RELAXED,
                                 __HIP_MEMORY_SCOPE_AGENT) < target)
          __builtin_amdgcn_s_sleep(2);
        __builtin_amdgcn_fence(__ATOMIC_ACQUIRE, "agent");
      }
      __syncthreads();
    }

    const int lvl = stage - layer;
    if (lvl >= 0 && lvl < NLVL) {
      // ---- stage A-tile: x part (k 0..127) and m part (k 128..255) ----
      {
        const int sub = tid >> 4;          // 0..15: row within a 16-row group
        const int c8  = (tid & 15) * 8;    // element offset, 16 B per thread
        uint4 z4; z4.x = z4.y = z4.z = z4.w = 0u;
        #pragma unroll
        for (int it = 0; it < 4; ++it) {
          const int row  = it * 16 + sub;
          const int lrow = blk * MT + row;
          const bool valid = (lrow < NPL);
          uint4* dx = (uint4*)(sA + row * ASTR + c8);
          *dx = valid ? *(const uint4*)(x + (size_t)(lvl * NPL + lrow) * HD + c8) : z4;
          uint4* dm = (uint4*)(sA + row * ASTR + HD + c8);
          if (lvl > 0 && valid) {
            const int eb = (lvl - 1) * EPL + lrow * DEG;
            const int4 e0 = *(const int4*)(esrc + eb);
            const int4 e1 = *(const int4*)(esrc + eb + 4);
            const int srcs[8] = { e0.x, e0.y, e0.z, e0.w, e1.x, e1.y, e1.z, e1.w };
            float acc[8];
            #pragma unroll
            for (int i = 0; i < 8; ++i) acc[i] = 0.f;
            #pragma unroll
            for (int e = 0; e < 8; ++e) {
              const uint4 v = *(const uint4*)(h + (size_t)srcs[e] * HD + c8);
              acc[0] += bflo(v.x); acc[1] += bfhi(v.x);
              acc[2] += bflo(v.y); acc[3] += bfhi(v.y);
              acc[4] += bflo(v.z); acc[5] += bfhi(v.z);
              acc[6] += bflo(v.w); acc[7] += bfhi(v.w);
            }
            uint4 o;
            o.x = pack2(acc[0] * 0.125f, acc[1] * 0.125f);
            o.y = pack2(acc[2] * 0.125f, acc[3] * 0.125f);
            o.z = pack2(acc[4] * 0.125f, acc[5] * 0.125f);
            o.w = pack2(acc[6] * 0.125f, acc[7] * 0.125f);
            *dm = o;
          } else {
            *dm = z4;   // level 0: m = 0
          }
        }
      }
      __syncthreads();   // staging -> K-loop

      // acc[row-frag][gate-group]; bias folded into init (gh_n group gets 0)
      f32x16 acc[2][4];
      #pragma unroll
      for (int r = 0; r < 16; ++r) {
        acc[0][0][r] = b0; acc[1][0][r] = b0;
        acc[0][1][r] = b1; acc[1][1][r] = b1;
        acc[0][2][r] = b2; acc[1][2][r] = b2;
        acc[0][3][r] = 0.f; acc[1][3][r] = 0.f;
      }

      // ---- K loop: A from LDS, B fragment-major from global (L2-hot) ----
      #pragma unroll
      for (int t = 0; t < 16; ++t) {
        const short8 a0 = *(const short8*)(sA + (l31     ) * ASTR + t * 16 + lq * 8);
        const short8 a1 = *(const short8*)(sA + (32 + l31) * ASTR + t * 16 + lq * 8);
        const short8 bb0 = *(const short8*)(wlane + (size_t)((wv    ) * 16 + t) * 512);
        const short8 bb1 = *(const short8*)(wlane + (size_t)((wv + 4) * 16 + t) * 512);
        acc[0][0] = __builtin_amdgcn_mfma_f32_32x32x16_bf16(a0, bb0, acc[0][0], 0, 0, 0);
        acc[1][0] = __builtin_amdgcn_mfma_f32_32x32x16_bf16(a1, bb0, acc[1][0], 0, 0, 0);
        acc[0][1] = __builtin_amdgcn_mfma_f32_32x32x16_bf16(a0, bb1, acc[0][1], 0, 0, 0);
        acc[1][1] = __builtin_amdgcn_mfma_f32_32x32x16_bf16(a1, bb1, acc[1][1], 0, 0, 0);
        if (t < 8) {
          const short8 bb2 = *(const short8*)(wlane + (size_t)(128 + wv * 8 + t) * 512);
          acc[0][2] = __builtin_amdgcn_mfma_f32_32x32x16_bf16(a0, bb2, acc[0][2], 0, 0, 0);
          acc[1][2] = __builtin_amdgcn_mfma_f32_32x32x16_bf16(a1, bb2, acc[1][2], 0, 0, 0);
        } else {
          const short8 bb3 = *(const short8*)(wlane + (size_t)(160 + wv * 8 + (t - 8)) * 512);
          acc[0][3] = __builtin_amdgcn_mfma_f32_32x32x16_bf16(a0, bb3, acc[0][3], 0, 0, 0);
          acc[1][3] = __builtin_amdgcn_mfma_f32_32x32x16_bf16(a1, bb3, acc[1][3], 0, 0, 0);
        }
      }

      // ---- epilogue: r,z,n gates in-register; m from A-tile; bf16 store ----
      #pragma unroll
      for (int rf = 0; rf < 2; ++rf) {
        #pragma unroll
        for (int r = 0; r < 16; ++r) {
          const int rowe = rf * 32 + (r & 3) + 8 * (r >> 2) + 4 * lq;  // C-layout row
          const int lrow = blk * MT + rowe;
          if (lrow < NPL) {
            const float gr  = acc[rf][0][r];
            const float gz  = acc[rf][1][r];
            const float gxn = acc[rf][2][r];
            const float ghn = acc[rf][3][r];
            const float mv  = bf2f(sA[rowe * ASTR + HD + jcol]);
            const float rg  = fsig(gr);
            const float zg  = fsig(gz);
            const float ng  = ftanh(gxn + rg * ghn);
            const float hv  = (1.f - zg) * ng + zg * mv;
            h[(size_t)(lvl * NPL + lrow) * HD + jcol] = f2bf(hv);
          }
        }
      }
    }

    // ---- signal stage completion (uniform across all blocks) ----
    __syncthreads();   // drains this block's stores (vmcnt(0) before barrier)
    if (tid == 0)
      __hip_atomic_fetch_add(done, 1, __ATOMIC_RELEASE, __HIP_MEMORY_SCOPE_AGENT);
  }
}

extern "C" void kernel_launch(void* const* d_in, const int* in_sizes, int n_in,
                              void* d_out, int out_size, void* d_ws, size_t ws_size,
                              hipStream_t stream)
{
  (void)in_sizes; (void)n_in; (void)out_size; (void)ws_size;
  const float* feats = (const float*)d_in[0];
  const float* wx    = (const float*)d_in[1];
  const float* wh    = (const float*)d_in[2];
  const float* bias  = (const float*)d_in[3];
  const int*   esrc  = (const int*)d_in[4];
  const int*   imap  = (const int*)d_in[6];
  float* out = (float*)d_out;

  char* ws = (char*)d_ws;
  u16* bufA = (u16*)ws;                       // 51,200,000 B  (x, then h1)
  u16* bufB = (u16*)(ws + 51200000);          // 51,200,000 B  (h0)
  u16* wt   = (u16*)(ws + 102400000);         // 393,216 B  (2 x 192-tile frag-major)
  int* done = (int*)(ws + 102793216);         // 16 B barrier counter

  scatter_x<<<12500, 256, 0, stream>>>(feats, imap, bufA);
  build_wt<<<768, 256, 0, stream>>>(wx, wh, wt, done);

  level_all<<<GRID, 256, 0, stream>>>(bufA, bufB, wt, bias, esrc, done);

  gather_out<<<12500, 256, 0, stream>>>(bufA, imap, out);
}

// Round 6
// 538.636 us; speedup vs baseline: 2.2024x; 2.2024x over previous
//
#include <hip/hip_runtime.h>
#include <stdint.h>

#define N_NODES 200000
#define NPL     12500
#define NLVL    16
#define DEG     8
#define EPL     (NPL*DEG)     // 100000
#define HD      128
#define KTOT    256           // concat K: [x | m]
#define MT      32            // rows per block: grid 782 -> ~3 blocks/CU
#define NBLK    391           // ceil(12500/32)
#define ASTR    264           // A-tile row stride (bf16), +8 pad
#define WTL     98304         // Wt elems per layer: 192 tiles x 64 lanes x 8

typedef unsigned short u16;
typedef unsigned int   u32;

typedef __attribute__((ext_vector_type(8)))  short  short8;   // 8 bf16 = 4 VGPR (MFMA A/B frag)
typedef __attribute__((ext_vector_type(16))) float  f32x16;   // 32x32 MFMA C/D frag

__device__ __forceinline__ float bf2f(u32 u) { return __uint_as_float(u << 16); }
__device__ __forceinline__ float bflo(u32 u) { return __uint_as_float(u << 16); }
__device__ __forceinline__ float bfhi(u32 u) { return __uint_as_float(u & 0xFFFF0000u); }
__device__ __forceinline__ u16 f2bf(float f) {
  u32 u = __float_as_uint(f);
  return (u16)((u + 0x7FFFu + ((u >> 16) & 1u)) >> 16);   // RNE
}
__device__ __forceinline__ u32 pack2(float a, float b) {
  u32 ua = __float_as_uint(a), ub = __float_as_uint(b);
  ua = (ua + 0x7FFFu + ((ua >> 16) & 1u)) >> 16;
  ub = ((ub + 0x7FFFu + ((ub >> 16) & 1u)) >> 16) << 16;
  return ua | ub;
}
__device__ __forceinline__ float fsig(float x) {
  return __builtin_amdgcn_rcpf(1.f + __builtin_amdgcn_exp2f(-1.4426950408889634f * x));
}
__device__ __forceinline__ float ftanh(float x) {
  float t = __builtin_amdgcn_exp2f(2.8853900817779268f * x);   // e^(2x)
  return 1.f - 2.f * __builtin_amdgcn_rcpf(t + 1.f);           // inf-safe at both ends
}

// x init: x[index_map[i]] = bf16(features[i])
__global__ __launch_bounds__(256) void scatter_x(const float* __restrict__ f,
    const int* __restrict__ idx, u16* __restrict__ xb)
{
  const int t = blockIdx.x * 256 + threadIdx.x;   // 3.2M threads, 16 per row
  const int i = t >> 4, sg = (t & 15) * 8;
  const int d = idx[i];
  const float4 a = *(const float4*)(f + (size_t)i * HD + sg);
  const float4 b = *(const float4*)(f + (size_t)i * HD + sg + 4);
  uint4 o;
  o.x = pack2(a.x, a.y); o.y = pack2(a.z, a.w);
  o.z = pack2(b.x, b.y); o.w = pack2(b.z, b.w);
  *(uint4*)(xb + (size_t)d * HD + sg) = o;
}

// out[i] = fp32(h_final[index_map[i]])
__global__ __launch_bounds__(256) void gather_out(const u16* __restrict__ hb,
    const int* __restrict__ idx, float* __restrict__ o)
{
  const int t = blockIdx.x * 256 + threadIdx.x;
  const int i = t >> 4, sg = (t & 15) * 8;
  const int s = idx[i];
  const uint4 v = *(const uint4*)(hb + (size_t)s * HD + sg);
  float4 lo, hi;
  lo.x = bflo(v.x); lo.y = bfhi(v.x); lo.z = bflo(v.y); lo.w = bfhi(v.y);
  hi.x = bflo(v.z); hi.y = bfhi(v.z); hi.z = bflo(v.w); hi.w = bfhi(v.w);
  *(float4*)(o + (size_t)i * HD + sg)     = lo;
  *(float4*)(o + (size_t)i * HD + sg + 4) = hi;
}

// Fragment-major Wt: per layer, 192 tiles of (64 lanes x 8 k-elems) = 1 KB.
// A tile is one wave B-fragment for mfma_32x32x16_bf16: lane = lq*32+l31
// holds 8 consecutive k for col = g*32 + l31. Wave loads = 1 KB contiguous.
//   tiles [0,128):   RZ  (cols 0..255,  k 0..255):  tile = g*16 + t
//   tiles [128,160): GXN (cols 256..383, k 0..127): tile = 128 + g*8 + t
//   tiles [160,192): GHN (cols 384..511, k 128..255): tile = 160 + g*8 + (t-8)
// GXN k>=128 and GHN k<128 are structurally zero -> not stored, not multiplied.
__global__ __launch_bounds__(256) void build_wt(const float* __restrict__ wx,
    const float* __restrict__ wh, u16* __restrict__ wt)
{
  const int t = blockIdx.x * 256 + threadIdx.x;   // < 196608
  const int l = t / WTL;
  const int r = t - l * WTL;
  const int e = r & 7;
  const int chunk = r >> 3;
  const int lane = chunk & 63;
  const int tile = chunk >> 6;          // 0..191
  const int l31 = lane & 31, lq = lane >> 5;
  int col, k;
  if (tile < 128)      { col =       (tile >> 4) * 32 + l31; k =       (tile & 15) * 16 + lq * 8 + e; }
  else if (tile < 160) { col = 256 + ((tile - 128) >> 3) * 32 + l31; k = ((tile - 128) & 7) * 16 + lq * 8 + e; }
  else                 { col = 384 + ((tile - 160) >> 3) * 32 + l31; k = 128 + ((tile - 160) & 7) * 16 + lq * 8 + e; }
  float v;
  if (col < 384) {   // RZ full-K, GXN (k<128 by construction)
    v = (k < 128) ? wx[(size_t)(l * 128 + k) * 384 + col]
                  : wh[(size_t)l * 49152 + (size_t)(k - 128) * 384 + col];
  } else {           // GHN (k>=128 by construction)
    v = wh[(size_t)l * 49152 + (size_t)(k - 128) * 384 + (col - 128)];
  }
  wt[(size_t)l * WTL + r] = f2bf(v);
}

// Stage s: blocks [0,NBLK) do layer-0 level s; blocks [NBLK,2*NBLK) do
// layer-1 level s-1. A=[x|mean-of-8 h] (M=32,K=256) x fragment-major Wt.
// MT=32 retry on the frag-major structure (R1's MT=32 regression was on
// the old 512B-strided B-layout): grid 782 -> ~3 blocks/CU vs 1.5, forced
// 4 waves/EU (VGPR<=128; acc is 64). ~2x in-flight gather loads per CU to
// cover the ~34 MB/stage random HBM fetch the R5 counters exposed.
__global__ __launch_bounds__(256, 4) void level_step(
    u16* __restrict__ bufA, u16* __restrict__ bufB,
    const u16* __restrict__ wt, const float* __restrict__ bias,
    const int* __restrict__ esrc, int stage)
{
  __shared__ __align__(16) u16 sA[MT * ASTR];     // 16,896 B

  int blk = blockIdx.x, layer, lvl;
  if (blk < NBLK) { layer = 0; lvl = stage; }
  else            { layer = 1; lvl = stage - 1; blk -= NBLK; }
  if (lvl < 0 || lvl >= NLVL) return;

  const u16*   x  = layer ? bufB : bufA;          // L0: scattered x; L1: h0
  u16*         h  = layer ? bufA : bufB;          // L0: h0; L1: h1 (final)
  const u16*   Wt = wt  + (size_t)layer * WTL;
  const float* bs = bias + (size_t)layer * 384;

  const int tid = threadIdx.x;

  // ---- stage A-tile: x part (k 0..127) and m part (k 128..255) ----
  // Verified decomposition: 16 lanes/row x 16 B, 2 row-iterations of 16 rows.
  {
    const int sub = tid >> 4;          // 0..15: row within a 16-row group
    const int c8  = (tid & 15) * 8;    // element offset, 16 B per thread
    uint4 z4; z4.x = z4.y = z4.z = z4.w = 0u;
    #pragma unroll
    for (int it = 0; it < 2; ++it) {
      const int row  = it * 16 + sub;
      const int lrow = blk * MT + row;
      const bool valid = (lrow < NPL);
      uint4* dx = (uint4*)(sA + row * ASTR + c8);
      *dx = valid ? *(const uint4*)(x + (size_t)(lvl * NPL + lrow) * HD + c8) : z4;
      uint4* dm = (uint4*)(sA + row * ASTR + HD + c8);
      if (lvl > 0 && valid) {
        const int eb = (lvl - 1) * EPL + lrow * DEG;
        const int4 e0 = *(const int4*)(esrc + eb);
        const int4 e1 = *(const int4*)(esrc + eb + 4);
        const int srcs[8] = { e0.x, e0.y, e0.z, e0.w, e1.x, e1.y, e1.z, e1.w };
        float acc[8];
        #pragma unroll
        for (int i = 0; i < 8; ++i) acc[i] = 0.f;
        #pragma unroll
        for (int e = 0; e < 8; ++e) {
          const uint4 v = *(const uint4*)(h + (size_t)srcs[e] * HD + c8);
          acc[0] += bflo(v.x); acc[1] += bfhi(v.x);
          acc[2] += bflo(v.y); acc[3] += bfhi(v.y);
          acc[4] += bflo(v.z); acc[5] += bfhi(v.z);
          acc[6] += bflo(v.w); acc[7] += bfhi(v.w);
        }
        uint4 o;
        o.x = pack2(acc[0] * 0.125f, acc[1] * 0.125f);
        o.y = pack2(acc[2] * 0.125f, acc[3] * 0.125f);
        o.z = pack2(acc[4] * 0.125f, acc[5] * 0.125f);
        o.w = pack2(acc[6] * 0.125f, acc[7] * 0.125f);
        *dm = o;
      } else {
        *dm = z4;   // level 0: m = 0
      }
    }
  }
  __syncthreads();   // the only barrier: K-loop below is barrier-free

  const int wv = tid >> 6, lane = tid & 63;
  const int l31 = lane & 31, lq = lane >> 5;

  // acc[gate-group]; fp32 bias folded into init (gh_n group gets 0)
  f32x16 acc[4];
  {
    const float b0 = bs[      32 * wv + l31];
    const float b1 = bs[128 + 32 * wv + l31];
    const float b2 = bs[256 + 32 * wv + l31];
    #pragma unroll
    for (int r = 0; r < 16; ++r) {
      acc[0][r] = b0; acc[1][r] = b1; acc[2][r] = b2; acc[3][r] = 0.f;
    }
  }

  // ---- K loop over 16 k-steps: A from LDS, B fragment-major from global ----
  // RZ cols: groups wv (acc[0]) and wv+4 (acc[1]), all 16 steps.
  // GXN (acc[2]): steps 0..7 only; GHN (acc[3]): steps 8..15 only.
  const u16* wlane = Wt + (size_t)lane * 8;
  #pragma unroll
  for (int t = 0; t < 16; ++t) {
    const short8 a0  = *(const short8*)(sA + l31 * ASTR + t * 16 + lq * 8);
    const short8 bb0 = *(const short8*)(wlane + (size_t)((wv    ) * 16 + t) * 512);
    const short8 bb1 = *(const short8*)(wlane + (size_t)((wv + 4) * 16 + t) * 512);
    acc[0] = __builtin_amdgcn_mfma_f32_32x32x16_bf16(a0, bb0, acc[0], 0, 0, 0);
    acc[1] = __builtin_amdgcn_mfma_f32_32x32x16_bf16(a0, bb1, acc[1], 0, 0, 0);
    if (t < 8) {
      const short8 bb2 = *(const short8*)(wlane + (size_t)(128 + wv * 8 + t) * 512);
      acc[2] = __builtin_amdgcn_mfma_f32_32x32x16_bf16(a0, bb2, acc[2], 0, 0, 0);
    } else {
      const short8 bb3 = *(const short8*)(wlane + (size_t)(160 + wv * 8 + (t - 8)) * 512);
      acc[3] = __builtin_amdgcn_mfma_f32_32x32x16_bf16(a0, bb3, acc[3], 0, 0, 0);
    }
  }

  // ---- epilogue: r,z,n gates in-register; m from A-tile; bf16 store ----
  const int jcol = 32 * wv + l31;
  #pragma unroll
  for (int r = 0; r < 16; ++r) {
    const int rowe = (r & 3) + 8 * (r >> 2) + 4 * lq;  // C-layout row, 0..31
    const int lrow = blk * MT + rowe;
    if (lrow < NPL) {
      const float gr  = acc[0][r];
      const float gz  = acc[1][r];
      const float gxn = acc[2][r];
      const float ghn = acc[3][r];
      const float mv  = bf2f(sA[rowe * ASTR + HD + jcol]);
      const float rg  = fsig(gr);
      const float zg  = fsig(gz);
      const float ng  = ftanh(gxn + rg * ghn);
      const float hv  = (1.f - zg) * ng + zg * mv;
      h[(size_t)(lvl * NPL + lrow) * HD + jcol] = f2bf(hv);
    }
  }
}

extern "C" void kernel_launch(void* const* d_in, const int* in_sizes, int n_in,
                              void* d_out, int out_size, void* d_ws, size_t ws_size,
                              hipStream_t stream)
{
  (void)in_sizes; (void)n_in; (void)out_size; (void)ws_size;
  const float* feats = (const float*)d_in[0];
  const float* wx    = (const float*)d_in[1];
  const float* wh    = (const float*)d_in[2];
  const float* bias  = (const float*)d_in[3];
  const int*   esrc  = (const int*)d_in[4];
  const int*   imap  = (const int*)d_in[6];
  float* out = (float*)d_out;

  char* ws = (char*)d_ws;
  u16* bufA = (u16*)ws;                       // 51,200,000 B  (x, then h1)
  u16* bufB = (u16*)(ws + 51200000);          // 51,200,000 B  (h0)
  u16* wt   = (u16*)(ws + 102400000);         // 393,216 B  (2 x 192-tile frag-major)

  scatter_x<<<12500, 256, 0, stream>>>(feats, imap, bufA);
  build_wt<<<768, 256, 0, stream>>>(wx, wh, wt);

  for (int stage = 0; stage <= NLVL; ++stage)
    level_step<<<2 * NBLK, 256, 0, stream>>>(bufA, bufB, wt, bias, esrc, stage);

  gather_out<<<12500, 256, 0, stream>>>(bufA, imap, out);
}